// Round 10
// baseline (367.272 us; speedup 1.0000x reference)
//
#include <hip/hip_runtime.h>

#define N_NODES 100000
#define N_EDGES 1600000
#define NBUCK 196          // 512 nodes per bucket (dst >> 9)
#define BCAP 9600          // expected 8192 +- 91; >15 sigma headroom
#define CH 4096            // edges per multisplit chunk
#define NCHUNK ((N_EDGES + CH - 1) / CH)  // 391

typedef __attribute__((ext_vector_type(2))) _Float16 half2v;
typedef __attribute__((ext_vector_type(4))) _Float16 half4v;
typedef __attribute__((ext_vector_type(8))) _Float16 half8v;

__device__ __forceinline__ float4 loadX4(const float* X, size_t idx) {
    return *(const float4*)(X + idx);
}
__device__ __forceinline__ float4 loadX4(const _Float16* X, size_t idx) {
    half4v h = *(const half4v*)(X + idx);
    return make_float4((float)h.x, (float)h.y, (float)h.z, (float)h.w);
}

// ---------------- counting-sort CSR build (R9, unchanged) ----------------

__global__ __launch_bounds__(256) void zero_small(int* p, int n) {
    int i = blockIdx.x * blockDim.x + threadIdx.x;
    if (i < n) p[i] = 0;
}

__global__ __launch_bounds__(256) void multisplit(const int* __restrict__ src,
                                                  const int* __restrict__ dst,
                                                  int* cursor,
                                                  int* __restrict__ bucketed, int e) {
    __shared__ int cnt[NBUCK];
    __shared__ int basel[NBUCK];
    const int t = threadIdx.x;
    const int base_e = blockIdx.x * CH;

    int myS[16], myD[16];
    for (int i = t; i < NBUCK; i += 256) cnt[i] = 0;
    __syncthreads();

#pragma unroll
    for (int k = 0; k < 16; ++k) {
        int i = base_e + k * 256 + t;
        if (i < e) {
            myS[k] = src[i];
            myD[k] = dst[i];
            atomicAdd(&cnt[myD[k] >> 9], 1);
        } else {
            myD[k] = -1;
        }
    }
    __syncthreads();
    for (int i = t; i < NBUCK; i += 256) basel[i] = atomicAdd(&cursor[i], cnt[i]);
    __syncthreads();
    for (int i = t; i < NBUCK; i += 256) cnt[i] = 0;
    __syncthreads();

#pragma unroll
    for (int k = 0; k < 16; ++k) {
        if (myD[k] >= 0) {
            int b = myD[k] >> 9;
            int pos = basel[b] + atomicAdd(&cnt[b], 1);
            if (pos < BCAP)
                bucketed[(size_t)b * BCAP + pos] = ((myD[k] & 511) << 17) | myS[k];
        }
    }
}

__global__ __launch_bounds__(256) void bucket_scan(const int* __restrict__ cursor,
                                                   int* __restrict__ gbase) {
    __shared__ int sm[256];
    const int t = threadIdx.x;
    int v = (t < NBUCK) ? cursor[t] : 0;
    sm[t] = v;
    __syncthreads();
    for (int off = 1; off < 256; off <<= 1) {
        int u = (t >= off) ? sm[t - off] : 0;
        __syncthreads();
        sm[t] += u;
        __syncthreads();
    }
    if (t < NBUCK) gbase[t] = sm[t] - v;
    if (t == NBUCK - 1) gbase[NBUCK] = sm[t];
}

__global__ __launch_bounds__(512) void build_csr(const int* __restrict__ bucketed,
                                                 const int* __restrict__ gbase,
                                                 int* __restrict__ row_ptr,
                                                 float* __restrict__ dinv,
                                                 int* __restrict__ csr_src, int n) {
    __shared__ int vals[BCAP];
    __shared__ int cnt[512];
    __shared__ int lcur[512];
    const int b = blockIdx.x;
    const int t = threadIdx.x;
    const int nb0 = b * 512;
    const int nn = min(512, n - nb0);
    const int gb = gbase[b];
    const int m = gbase[b + 1] - gb;

    cnt[t] = 0;
    __syncthreads();
    for (int i = t; i < m; i += 512) {
        int v = bucketed[(size_t)b * BCAP + i];
        vals[i] = v;
        atomicAdd(&cnt[v >> 17], 1);
    }
    __syncthreads();

    int deg = cnt[t];
    for (int off = 1; off < 512; off <<= 1) {
        int u = (t >= off) ? cnt[t - off] : 0;
        __syncthreads();
        cnt[t] += u;
        __syncthreads();
    }
    int offv = cnt[t] - deg;
    __syncthreads();
    cnt[t] = offv;
    lcur[t] = 0;
    if (t < nn) {
        row_ptr[nb0 + t] = gb + offv;
        dinv[nb0 + t] = rsqrtf((float)(deg + 1));
    }
    if (b == NBUCK - 1 && t == 0) row_ptr[n] = gb + m;
    __syncthreads();

    for (int i = t; i < m; i += 512) {
        int v = vals[i];
        int node = v >> 17;
        int pos = atomicAdd(&lcur[node], 1);
        csr_src[gb + cnt[node] + pos] = v & 0x1FFFF;
    }
}

// ---------------- gemm64 v2: Y[N,64] = fp16(dinv[row] * X[N,K] @ W[K,64]) ----------------
// 64x64 tile per 256-thread block, thread owns 4x4. W staged TRANSPOSED.
// Per 4 k-steps: 8x ds_read_b128 feed 64 v_fma (vs 20 issues per 16 FMA before).

template <int K, typename XT>
__global__ __launch_bounds__(256) void gemm64_rt(const XT* __restrict__ X,
                                                 const float* __restrict__ W,
                                                 const float* __restrict__ dinv,
                                                 _Float16* __restrict__ Y, int n) {
    constexpr int COUT = 64;
    constexpr int KC = 64;
    constexpr int S = KC + 4;      // 68 floats = 272B, 16B-aligned rows
    constexpr int NCH = K / KC;
    __shared__ float Xl[64 * S];
    __shared__ float Wt[64 * S];   // transposed: Wt[c][k]

    const int t = threadIdx.x;
    const int row0 = blockIdx.x * 64;
    const int cg = (t & 15) * 4;
    const int rg = (t >> 4) * 4;

    float acc[4][4] = {};

#pragma unroll
    for (int ch = 0; ch < NCH; ++ch) {
        const int k0 = ch * KC;
        // stage X rows (cvt to fp32 if fp16 input)
        for (int i = t; i < 64 * KC / 4; i += 256) {
            int r = i >> 4;
            int k = (i & 15) * 4;
            int grow = min(row0 + r, n - 1);
            *(float4*)(Xl + r * S + k) = loadX4(X, (size_t)grow * K + k0 + k);
        }
        // stage W transposed: read W[k][c] coalesced, write Wt[c][k]
        for (int i = t; i < KC * COUT; i += 256) {
            int c = i & 63, k = i >> 6;
            Wt[c * S + k] = W[(size_t)(k0 + k) * COUT + c];
        }
        __syncthreads();

#pragma unroll 2
        for (int k4 = 0; k4 < KC; k4 += 4) {
            float4 xv0 = *(const float4*)(Xl + (rg + 0) * S + k4);
            float4 xv1 = *(const float4*)(Xl + (rg + 1) * S + k4);
            float4 xv2 = *(const float4*)(Xl + (rg + 2) * S + k4);
            float4 xv3 = *(const float4*)(Xl + (rg + 3) * S + k4);
            float4 wv0 = *(const float4*)(Wt + (cg + 0) * S + k4);
            float4 wv1 = *(const float4*)(Wt + (cg + 1) * S + k4);
            float4 wv2 = *(const float4*)(Wt + (cg + 2) * S + k4);
            float4 wv3 = *(const float4*)(Wt + (cg + 3) * S + k4);
            const float4 xv[4] = {xv0, xv1, xv2, xv3};
            const float4 wv[4] = {wv0, wv1, wv2, wv3};
#pragma unroll
            for (int r = 0; r < 4; ++r)
#pragma unroll
                for (int c = 0; c < 4; ++c) {
                    acc[r][c] += xv[r].x * wv[c].x;
                    acc[r][c] += xv[r].y * wv[c].y;
                    acc[r][c] += xv[r].z * wv[c].z;
                    acc[r][c] += xv[r].w * wv[c].w;
                }
        }
        __syncthreads();
    }

#pragma unroll
    for (int r = 0; r < 4; ++r) {
        int row = row0 + rg + r;
        if (row < n) {
            float d = dinv[row];
            half4v o = { (_Float16)(d * acc[r][0]), (_Float16)(d * acc[r][1]),
                         (_Float16)(d * acc[r][2]), (_Float16)(d * acc[r][3]) };
            *(half4v*)(Y + (size_t)row * COUT + cg) = o;
        }
    }
}

// ---------------- gemm40 (old structure, fp16 in): Y[N,40] fp16 ----------------

template <int K, int COUT, typename XT>
__global__ __launch_bounds__(256) void gemm_rt(const XT* __restrict__ X,
                                               const float* __restrict__ W,
                                               const float* __restrict__ dinv,
                                               _Float16* __restrict__ Y, int n) {
    constexpr int KC = 64;
    constexpr int S = KC + 4;
    constexpr int NCH = K / KC;
    __shared__ float Xl[64 * S];
    __shared__ float Wl[KC * COUT];

    const int t = threadIdx.x;
    const int row0 = blockIdx.x * 64;
    const int cg = (t & 15) * 4;
    const int rg = (t >> 4) * 4;

    float acc[4][4] = {};

#pragma unroll
    for (int ch = 0; ch < NCH; ++ch) {
        const int k0 = ch * KC;
        for (int i = t; i < 64 * KC / 4; i += 256) {
            int r = i >> 4;
            int k = (i & 15) * 4;
            int grow = min(row0 + r, n - 1);
            *(float4*)(Xl + r * S + k) = loadX4(X, (size_t)grow * K + k0 + k);
        }
        for (int i = t; i < KC * COUT / 4; i += 256) {
            *(float4*)(Wl + i * 4) = *(const float4*)(W + (size_t)k0 * COUT + (size_t)i * 4);
        }
        __syncthreads();

        if (cg < COUT) {
#pragma unroll 4
            for (int k = 0; k < KC; ++k) {
                float4 w = *(const float4*)(Wl + k * COUT + cg);
                float x0 = Xl[(rg + 0) * S + k];
                float x1 = Xl[(rg + 1) * S + k];
                float x2 = Xl[(rg + 2) * S + k];
                float x3 = Xl[(rg + 3) * S + k];
                acc[0][0] += x0 * w.x; acc[0][1] += x0 * w.y; acc[0][2] += x0 * w.z; acc[0][3] += x0 * w.w;
                acc[1][0] += x1 * w.x; acc[1][1] += x1 * w.y; acc[1][2] += x1 * w.z; acc[1][3] += x1 * w.w;
                acc[2][0] += x2 * w.x; acc[2][1] += x2 * w.y; acc[2][2] += x2 * w.z; acc[2][3] += x2 * w.w;
                acc[3][0] += x3 * w.x; acc[3][1] += x3 * w.y; acc[3][2] += x3 * w.z; acc[3][3] += x3 * w.w;
            }
        }
        __syncthreads();
    }

    if (cg < COUT) {
#pragma unroll
        for (int r = 0; r < 4; ++r) {
            int row = row0 + rg + r;
            if (row < n) {
                float d = dinv[row];
                half4v o = { (_Float16)(d * acc[r][0]), (_Float16)(d * acc[r][1]),
                             (_Float16)(d * acc[r][2]), (_Float16)(d * acc[r][3]) };
                *(half4v*)(Y + (size_t)row * COUT + cg) = o;
            }
        }
    }
}

// ---------------- aggregation v2, COUT=64, fp16 gather, fp16 out ----------------
// 8 groups of 8 lanes; group g reads edge (j+g)'s 16B row-part (half8) ->
// one wave-issue covers 8 full 128B rows. Per-lane 8 fp32 accumulators for
// channels c8*8..+7; butterfly xor{8,16,32}; lanes 0-7 store one half8 each.

template <bool RELU>
__global__ __launch_bounds__(256) void aggregate64b(const _Float16* __restrict__ tS,
                                                    const int* __restrict__ row_ptr,
                                                    const int* __restrict__ csr_src,
                                                    const float* __restrict__ dinv,
                                                    const float* __restrict__ bias,
                                                    _Float16* __restrict__ out, int n) {
    const int lane = threadIdx.x & 63;
    const int node = blockIdx.x * 4 + (threadIdx.x >> 6);
    if (node >= n) return;
    const int g = lane >> 3;     // edge sub-slot 0..7
    const int c8 = lane & 7;     // 16B chunk within row (channels c8*8..+7)
    const half8v* tS8 = (const half8v*)tS;

    const int beg = row_ptr[node];
    const int cnt = row_ptr[node + 1] - beg;

    float acc[8] = {};

    for (int j0 = 0; j0 < cnt; j0 += 64) {
        const int m = min(64, cnt - j0);
        int sj = csr_src[beg + j0 + min(lane, m - 1)];

        int j = 0;
        for (; j + 16 <= m; j += 16) {
            int e0 = __shfl(sj, j + g);
            int e1 = __shfl(sj, j + 8 + g);
            half8v v0 = tS8[(size_t)e0 * 8 + c8];
            half8v v1 = tS8[(size_t)e1 * 8 + c8];
#pragma unroll
            for (int i = 0; i < 8; ++i) acc[i] += (float)v0[i];
#pragma unroll
            for (int i = 0; i < 8; ++i) acc[i] += (float)v1[i];
        }
        for (; j + 8 <= m; j += 8) {
            int e0 = __shfl(sj, j + g);
            half8v v0 = tS8[(size_t)e0 * 8 + c8];
#pragma unroll
            for (int i = 0; i < 8; ++i) acc[i] += (float)v0[i];
        }
        if (j < m) {
            int idx = j + g;
            int e0 = __shfl(sj, min(idx, m - 1));
            half8v v = tS8[(size_t)e0 * 8 + c8];
            float flag = (idx < m) ? 1.0f : 0.0f;
#pragma unroll
            for (int i = 0; i < 8; ++i) acc[i] = fmaf(flag, (float)v[i], acc[i]);
        }
    }

#pragma unroll
    for (int off = 8; off < 64; off <<= 1) {
#pragma unroll
        for (int i = 0; i < 8; ++i) acc[i] += __shfl_xor(acc[i], off);
    }

    if (lane < 8) {
        half8v selfh = tS8[(size_t)node * 8 + c8];
        float4 b0 = *(const float4*)(bias + c8 * 8);
        float4 b1 = *(const float4*)(bias + c8 * 8 + 4);
        const float bb[8] = {b0.x, b0.y, b0.z, b0.w, b1.x, b1.y, b1.z, b1.w};
        float d = dinv[node];
        half8v o;
#pragma unroll
        for (int i = 0; i < 8; ++i) {
            float v = bb[i] + d * (acc[i] + (float)selfh[i]);
            if (RELU) v = fmaxf(v, 0.0f);
            o[i] = (_Float16)v;
        }
        ((half8v*)out)[(size_t)node * 8 + c8] = o;
    }
}

// ---------------- aggregation, COUT=40, fp16 gather, fp32 out (R9) ----------------

__global__ __launch_bounds__(256) void aggregate40v(const _Float16* __restrict__ tS,
                                                    const int* __restrict__ row_ptr,
                                                    const int* __restrict__ csr_src,
                                                    const float* __restrict__ dinv,
                                                    const float* __restrict__ bias,
                                                    float* __restrict__ out, int n) {
    const int lane = threadIdx.x & 63;
    const int node = blockIdx.x * 4 + (threadIdx.x >> 6);
    if (node >= n) return;
    const int g = lane / 20;
    const int c2 = lane - 20 * g;
    const bool act = (g < 3);
    const half2v* tS2 = (const half2v*)tS;

    const int beg = row_ptr[node];
    const int cnt = row_ptr[node + 1] - beg;

    float2 a0 = {0,0}, a1 = {0,0}, a2 = {0,0}, a3 = {0,0};

    for (int j0 = 0; j0 < cnt; j0 += 64) {
        const int m = min(64, cnt - j0);
        int sj = (lane < m) ? csr_src[beg + j0 + lane] : 0;

        int j = 0;
        for (; j + 12 <= m; j += 12) {
            int i0 = j + g, i1 = j + 3 + g, i2 = j + 6 + g, i3 = j + 9 + g;
            int e0 = __shfl(sj, i0 < m ? i0 : 0);
            int e1 = __shfl(sj, i1 < m ? i1 : 0);
            int e2 = __shfl(sj, i2 < m ? i2 : 0);
            int e3 = __shfl(sj, i3 < m ? i3 : 0);
            half2v v0 = tS2[(size_t)e0 * 20 + c2];
            half2v v1 = tS2[(size_t)e1 * 20 + c2];
            half2v v2 = tS2[(size_t)e2 * 20 + c2];
            half2v v3 = tS2[(size_t)e3 * 20 + c2];
            if (act) {
                a0.x += (float)v0.x; a0.y += (float)v0.y;
                a1.x += (float)v1.x; a1.y += (float)v1.y;
                a2.x += (float)v2.x; a2.y += (float)v2.y;
                a3.x += (float)v3.x; a3.y += (float)v3.y;
            }
        }
        for (; j + 3 <= m; j += 3) {
            int i0 = j + g;
            int e0 = __shfl(sj, i0 < m ? i0 : 0);
            half2v v0 = tS2[(size_t)e0 * 20 + c2];
            if (act) { a0.x += (float)v0.x; a0.y += (float)v0.y; }
        }
        if (j < m) {
            int idx = j + g;
            int e0 = __shfl(sj, idx < m ? idx : m - 1);
            half2v v = tS2[(size_t)e0 * 20 + c2];
            if (act && idx < m) { a0.x += (float)v.x; a0.y += (float)v.y; }
        }
    }

    float2 s;
    s.x = (a0.x + a1.x) + (a2.x + a3.x);
    s.y = (a0.y + a1.y) + (a2.y + a3.y);
    float sx1 = __shfl(s.x, lane + 20), sy1 = __shfl(s.y, lane + 20);
    float sx2 = __shfl(s.x, lane + 40), sy2 = __shfl(s.y, lane + 40);
    if (lane < 20) {
        s.x += sx1 + sx2;
        s.y += sy1 + sy2;
        half2v selfh = tS2[(size_t)node * 20 + c2];
        float2 b = ((const float2*)bias)[c2];
        float d = dinv[node];
        float2 o;
        o.x = b.x + d * (s.x + (float)selfh.x);
        o.y = b.y + d * (s.y + (float)selfh.y);
        ((float2*)out)[(size_t)node * 20 + c2] = o;
    }
}

// ---------------- launch ----------------

extern "C" void kernel_launch(void* const* d_in, const int* in_sizes, int n_in,
                              void* d_out, int out_size, void* d_ws, size_t ws_size,
                              hipStream_t stream) {
    const float* x  = (const float*)d_in[0];
    const int*   ei = (const int*)d_in[1];
    const int*   src = ei;
    const int*   dst = ei + N_EDGES;
    const float* W1 = (const float*)d_in[2];
    const float* b1 = (const float*)d_in[3];
    const float* W2 = (const float*)d_in[4];
    const float* b2 = (const float*)d_in[5];
    const float* W3 = (const float*)d_in[6];
    const float* b3 = (const float*)d_in[7];
    float* out = (float*)d_out;

    const int N = N_NODES, E = N_EDGES;

    char* p = (char*)d_ws;
    int*   cursor   = (int*)p;              p += 256 * 4;
    int*   gbase    = (int*)p;              p += 256 * 4;
    float* dinv     = (float*)p;            p += (size_t)N * 4;
    int*   row_ptr  = (int*)p;              p += (size_t)(N + 4) * 4;
    int*   bucketed = (int*)p;              p += (size_t)NBUCK * BCAP * 4;
    int*   csr_src  = (int*)p;              p += (size_t)E * 4;
    p = (char*)(((size_t)p + 15) & ~(size_t)15);
    _Float16* bufA  = (_Float16*)p;         p += (size_t)N * 64 * 2;  // fp16 tS
    p = (char*)(((size_t)p + 15) & ~(size_t)15);
    _Float16* bufB  = (_Float16*)p;         p += (size_t)N * 64 * 2;  // fp16 h

    // ---- counting-sort CSR build ----
    zero_small<<<1, 256, 0, stream>>>(cursor, NBUCK);
    multisplit<<<NCHUNK, 256, 0, stream>>>(src, dst, cursor, bucketed, E);
    bucket_scan<<<1, 256, 0, stream>>>(cursor, gbase);
    build_csr<<<NBUCK, 512, 0, stream>>>(bucketed, gbase, row_ptr, dinv, csr_src, N);

    const int aggGrid = (N + 3) / 4;
    const int gemmGrid = (N + 63) / 64;

    // layer 1: x fp32 -> tS fp16; aggregate+relu -> h fp16
    gemm64_rt<128, float><<<gemmGrid, 256, 0, stream>>>(x, W1, dinv, bufA, N);
    aggregate64b<true><<<aggGrid, 256, 0, stream>>>(bufA, row_ptr, csr_src, dinv, b1, bufB, N);

    // layer 2: h fp16 -> tS fp16; aggregate+relu -> h fp16
    gemm64_rt<64, _Float16><<<gemmGrid, 256, 0, stream>>>(bufB, W2, dinv, bufA, N);
    aggregate64b<true><<<aggGrid, 256, 0, stream>>>(bufA, row_ptr, csr_src, dinv, b2, bufB, N);

    // layer 3: h fp16 -> tS40 fp16; aggregate -> out fp32
    gemm_rt<64, 40, _Float16><<<gemmGrid, 256, 0, stream>>>(bufB, W3, dinv, bufA, N);
    aggregate40v<<<aggGrid, 256, 0, stream>>>(bufA, row_ptr, csr_src, dinv, b3, out, N);
}

// Round 11
// 346.414 us; speedup vs baseline: 1.0602x; 1.0602x over previous
//
#include <hip/hip_runtime.h>

#define N_NODES 100000
#define N_EDGES 1600000
#define NBUCK 196          // 512 nodes per bucket (dst >> 9)
#define BCAP 9600          // expected 8192 +- 91; >15 sigma headroom
#define CH 4096            // edges per multisplit chunk
#define NCHUNK ((N_EDGES + CH - 1) / CH)  // 391

typedef __attribute__((ext_vector_type(2))) _Float16 half2v;
typedef __attribute__((ext_vector_type(4))) _Float16 half4v;
typedef __attribute__((ext_vector_type(8))) _Float16 half8v;

__device__ __forceinline__ float4 loadX4(const float* X, size_t idx) {
    return *(const float4*)(X + idx);
}
__device__ __forceinline__ float4 loadX4(const _Float16* X, size_t idx) {
    half4v h = *(const half4v*)(X + idx);
    return make_float4((float)h.x, (float)h.y, (float)h.z, (float)h.w);
}

// ---------------- counting-sort CSR build (R9, unchanged) ----------------

__global__ __launch_bounds__(256) void zero_small(int* p, int n) {
    int i = blockIdx.x * blockDim.x + threadIdx.x;
    if (i < n) p[i] = 0;
}

__global__ __launch_bounds__(256) void multisplit(const int* __restrict__ src,
                                                  const int* __restrict__ dst,
                                                  int* cursor,
                                                  int* __restrict__ bucketed, int e) {
    __shared__ int cnt[NBUCK];
    __shared__ int basel[NBUCK];
    const int t = threadIdx.x;
    const int base_e = blockIdx.x * CH;

    int myS[16], myD[16];
    for (int i = t; i < NBUCK; i += 256) cnt[i] = 0;
    __syncthreads();

#pragma unroll
    for (int k = 0; k < 16; ++k) {
        int i = base_e + k * 256 + t;
        if (i < e) {
            myS[k] = src[i];
            myD[k] = dst[i];
            atomicAdd(&cnt[myD[k] >> 9], 1);
        } else {
            myD[k] = -1;
        }
    }
    __syncthreads();
    for (int i = t; i < NBUCK; i += 256) basel[i] = atomicAdd(&cursor[i], cnt[i]);
    __syncthreads();
    for (int i = t; i < NBUCK; i += 256) cnt[i] = 0;
    __syncthreads();

#pragma unroll
    for (int k = 0; k < 16; ++k) {
        if (myD[k] >= 0) {
            int b = myD[k] >> 9;
            int pos = basel[b] + atomicAdd(&cnt[b], 1);
            if (pos < BCAP)
                bucketed[(size_t)b * BCAP + pos] = ((myD[k] & 511) << 17) | myS[k];
        }
    }
}

__global__ __launch_bounds__(256) void bucket_scan(const int* __restrict__ cursor,
                                                   int* __restrict__ gbase) {
    __shared__ int sm[256];
    const int t = threadIdx.x;
    int v = (t < NBUCK) ? cursor[t] : 0;
    sm[t] = v;
    __syncthreads();
    for (int off = 1; off < 256; off <<= 1) {
        int u = (t >= off) ? sm[t - off] : 0;
        __syncthreads();
        sm[t] += u;
        __syncthreads();
    }
    if (t < NBUCK) gbase[t] = sm[t] - v;
    if (t == NBUCK - 1) gbase[NBUCK] = sm[t];
}

__global__ __launch_bounds__(512) void build_csr(const int* __restrict__ bucketed,
                                                 const int* __restrict__ gbase,
                                                 int* __restrict__ row_ptr,
                                                 float* __restrict__ dinv,
                                                 int* __restrict__ csr_src, int n) {
    __shared__ int vals[BCAP];
    __shared__ int cnt[512];
    __shared__ int lcur[512];
    const int b = blockIdx.x;
    const int t = threadIdx.x;
    const int nb0 = b * 512;
    const int nn = min(512, n - nb0);
    const int gb = gbase[b];
    const int m = gbase[b + 1] - gb;

    cnt[t] = 0;
    __syncthreads();
    for (int i = t; i < m; i += 512) {
        int v = bucketed[(size_t)b * BCAP + i];
        vals[i] = v;
        atomicAdd(&cnt[v >> 17], 1);
    }
    __syncthreads();

    int deg = cnt[t];
    for (int off = 1; off < 512; off <<= 1) {
        int u = (t >= off) ? cnt[t - off] : 0;
        __syncthreads();
        cnt[t] += u;
        __syncthreads();
    }
    int offv = cnt[t] - deg;
    __syncthreads();
    cnt[t] = offv;
    lcur[t] = 0;
    if (t < nn) {
        row_ptr[nb0 + t] = gb + offv;
        dinv[nb0 + t] = rsqrtf((float)(deg + 1));
    }
    if (b == NBUCK - 1 && t == 0) row_ptr[n] = gb + m;
    __syncthreads();

    for (int i = t; i < m; i += 512) {
        int v = vals[i];
        int node = v >> 17;
        int pos = atomicAdd(&lcur[node], 1);
        csr_src[gb + cnt[node] + pos] = v & 0x1FFFF;
    }
}

// ---------------- GEMM (R9 structure, conflict-free): Y = fp16(dinv * X @ W) ----------------
// Per k: 1x ds_read_b128 (W, 2-way bank alias = free) + 4x broadcast ds_read_b32 (X).

template <int K, int COUT, typename XT>
__global__ __launch_bounds__(256) void gemm_rt(const XT* __restrict__ X,
                                               const float* __restrict__ W,
                                               const float* __restrict__ dinv,
                                               _Float16* __restrict__ Y, int n) {
    constexpr int KC = 64;
    constexpr int S = KC + 4;
    constexpr int NCH = K / KC;
    __shared__ float Xl[64 * S];
    __shared__ float Wl[KC * COUT];

    const int t = threadIdx.x;
    const int row0 = blockIdx.x * 64;
    const int cg = (t & 15) * 4;
    const int rg = (t >> 4) * 4;

    float acc[4][4] = {};

#pragma unroll
    for (int ch = 0; ch < NCH; ++ch) {
        const int k0 = ch * KC;
        for (int i = t; i < 64 * KC / 4; i += 256) {
            int r = i >> 4;
            int k = (i & 15) * 4;
            int grow = min(row0 + r, n - 1);
            *(float4*)(Xl + r * S + k) = loadX4(X, (size_t)grow * K + k0 + k);
        }
        for (int i = t; i < KC * COUT / 4; i += 256) {
            *(float4*)(Wl + i * 4) = *(const float4*)(W + (size_t)k0 * COUT + (size_t)i * 4);
        }
        __syncthreads();

        if (cg < COUT) {
#pragma unroll 4
            for (int k = 0; k < KC; ++k) {
                float4 w = *(const float4*)(Wl + k * COUT + cg);
                float x0 = Xl[(rg + 0) * S + k];
                float x1 = Xl[(rg + 1) * S + k];
                float x2 = Xl[(rg + 2) * S + k];
                float x3 = Xl[(rg + 3) * S + k];
                acc[0][0] += x0 * w.x; acc[0][1] += x0 * w.y; acc[0][2] += x0 * w.z; acc[0][3] += x0 * w.w;
                acc[1][0] += x1 * w.x; acc[1][1] += x1 * w.y; acc[1][2] += x1 * w.z; acc[1][3] += x1 * w.w;
                acc[2][0] += x2 * w.x; acc[2][1] += x2 * w.y; acc[2][2] += x2 * w.z; acc[2][3] += x2 * w.w;
                acc[3][0] += x3 * w.x; acc[3][1] += x3 * w.y; acc[3][2] += x3 * w.z; acc[3][3] += x3 * w.w;
            }
        }
        __syncthreads();
    }

    if (cg < COUT) {
#pragma unroll
        for (int r = 0; r < 4; ++r) {
            int row = row0 + rg + r;
            if (row < n) {
                float d = dinv[row];
                half4v o = { (_Float16)(d * acc[r][0]), (_Float16)(d * acc[r][1]),
                             (_Float16)(d * acc[r][2]), (_Float16)(d * acc[r][3]) };
                *(half4v*)(Y + (size_t)row * COUT + cg) = o;
            }
        }
    }
}

// ---------------- aggregation v2, COUT=64, fp16 gather, fp16 out (R10) ----------------
// 8 groups of 8 lanes; group g reads edge (j+g)'s 16B row-part (half8) ->
// one wave-issue covers 8 full 128B rows. Per-lane 8 fp32 accumulators;
// butterfly xor{8,16,32}; lanes 0-7 store one half8 each.

template <bool RELU>
__global__ __launch_bounds__(256) void aggregate64b(const _Float16* __restrict__ tS,
                                                    const int* __restrict__ row_ptr,
                                                    const int* __restrict__ csr_src,
                                                    const float* __restrict__ dinv,
                                                    const float* __restrict__ bias,
                                                    _Float16* __restrict__ out, int n) {
    const int lane = threadIdx.x & 63;
    const int node = blockIdx.x * 4 + (threadIdx.x >> 6);
    if (node >= n) return;
    const int g = lane >> 3;     // edge sub-slot 0..7
    const int c8 = lane & 7;     // 16B chunk within row
    const half8v* tS8 = (const half8v*)tS;

    const int beg = row_ptr[node];
    const int cnt = row_ptr[node + 1] - beg;

    float acc[8] = {};

    for (int j0 = 0; j0 < cnt; j0 += 64) {
        const int m = min(64, cnt - j0);
        int sj = csr_src[beg + j0 + min(lane, m - 1)];

        int j = 0;
        for (; j + 16 <= m; j += 16) {
            int e0 = __shfl(sj, j + g);
            int e1 = __shfl(sj, j + 8 + g);
            half8v v0 = tS8[(size_t)e0 * 8 + c8];
            half8v v1 = tS8[(size_t)e1 * 8 + c8];
#pragma unroll
            for (int i = 0; i < 8; ++i) acc[i] += (float)v0[i];
#pragma unroll
            for (int i = 0; i < 8; ++i) acc[i] += (float)v1[i];
        }
        for (; j + 8 <= m; j += 8) {
            int e0 = __shfl(sj, j + g);
            half8v v0 = tS8[(size_t)e0 * 8 + c8];
#pragma unroll
            for (int i = 0; i < 8; ++i) acc[i] += (float)v0[i];
        }
        if (j < m) {
            int idx = j + g;
            int e0 = __shfl(sj, min(idx, m - 1));
            half8v v = tS8[(size_t)e0 * 8 + c8];
            float flag = (idx < m) ? 1.0f : 0.0f;
#pragma unroll
            for (int i = 0; i < 8; ++i) acc[i] = fmaf(flag, (float)v[i], acc[i]);
        }
    }

#pragma unroll
    for (int off = 8; off < 64; off <<= 1) {
#pragma unroll
        for (int i = 0; i < 8; ++i) acc[i] += __shfl_xor(acc[i], off);
    }

    if (lane < 8) {
        half8v selfh = tS8[(size_t)node * 8 + c8];
        float4 b0 = *(const float4*)(bias + c8 * 8);
        float4 b1 = *(const float4*)(bias + c8 * 8 + 4);
        const float bb[8] = {b0.x, b0.y, b0.z, b0.w, b1.x, b1.y, b1.z, b1.w};
        float d = dinv[node];
        half8v o;
#pragma unroll
        for (int i = 0; i < 8; ++i) {
            float v = bb[i] + d * (acc[i] + (float)selfh[i]);
            if (RELU) v = fmaxf(v, 0.0f);
            o[i] = (_Float16)v;
        }
        ((half8v*)out)[(size_t)node * 8 + c8] = o;
    }
}

// ---------------- aggregation, COUT=40, fp16 gather, fp32 out (R9) ----------------

__global__ __launch_bounds__(256) void aggregate40v(const _Float16* __restrict__ tS,
                                                    const int* __restrict__ row_ptr,
                                                    const int* __restrict__ csr_src,
                                                    const float* __restrict__ dinv,
                                                    const float* __restrict__ bias,
                                                    float* __restrict__ out, int n) {
    const int lane = threadIdx.x & 63;
    const int node = blockIdx.x * 4 + (threadIdx.x >> 6);
    if (node >= n) return;
    const int g = lane / 20;
    const int c2 = lane - 20 * g;
    const bool act = (g < 3);
    const half2v* tS2 = (const half2v*)tS;

    const int beg = row_ptr[node];
    const int cnt = row_ptr[node + 1] - beg;

    float2 a0 = {0,0}, a1 = {0,0}, a2 = {0,0}, a3 = {0,0};

    for (int j0 = 0; j0 < cnt; j0 += 64) {
        const int m = min(64, cnt - j0);
        int sj = (lane < m) ? csr_src[beg + j0 + lane] : 0;

        int j = 0;
        for (; j + 12 <= m; j += 12) {
            int i0 = j + g, i1 = j + 3 + g, i2 = j + 6 + g, i3 = j + 9 + g;
            int e0 = __shfl(sj, i0 < m ? i0 : 0);
            int e1 = __shfl(sj, i1 < m ? i1 : 0);
            int e2 = __shfl(sj, i2 < m ? i2 : 0);
            int e3 = __shfl(sj, i3 < m ? i3 : 0);
            half2v v0 = tS2[(size_t)e0 * 20 + c2];
            half2v v1 = tS2[(size_t)e1 * 20 + c2];
            half2v v2 = tS2[(size_t)e2 * 20 + c2];
            half2v v3 = tS2[(size_t)e3 * 20 + c2];
            if (act) {
                a0.x += (float)v0.x; a0.y += (float)v0.y;
                a1.x += (float)v1.x; a1.y += (float)v1.y;
                a2.x += (float)v2.x; a2.y += (float)v2.y;
                a3.x += (float)v3.x; a3.y += (float)v3.y;
            }
        }
        for (; j + 3 <= m; j += 3) {
            int i0 = j + g;
            int e0 = __shfl(sj, i0 < m ? i0 : 0);
            half2v v0 = tS2[(size_t)e0 * 20 + c2];
            if (act) { a0.x += (float)v0.x; a0.y += (float)v0.y; }
        }
        if (j < m) {
            int idx = j + g;
            int e0 = __shfl(sj, idx < m ? idx : m - 1);
            half2v v = tS2[(size_t)e0 * 20 + c2];
            if (act && idx < m) { a0.x += (float)v.x; a0.y += (float)v.y; }
        }
    }

    float2 s;
    s.x = (a0.x + a1.x) + (a2.x + a3.x);
    s.y = (a0.y + a1.y) + (a2.y + a3.y);
    float sx1 = __shfl(s.x, lane + 20), sy1 = __shfl(s.y, lane + 20);
    float sx2 = __shfl(s.x, lane + 40), sy2 = __shfl(s.y, lane + 40);
    if (lane < 20) {
        s.x += sx1 + sx2;
        s.y += sy1 + sy2;
        half2v selfh = tS2[(size_t)node * 20 + c2];
        float2 b = ((const float2*)bias)[c2];
        float d = dinv[node];
        float2 o;
        o.x = b.x + d * (s.x + (float)selfh.x);
        o.y = b.y + d * (s.y + (float)selfh.y);
        ((float2*)out)[(size_t)node * 20 + c2] = o;
    }
}

// ---------------- launch ----------------

extern "C" void kernel_launch(void* const* d_in, const int* in_sizes, int n_in,
                              void* d_out, int out_size, void* d_ws, size_t ws_size,
                              hipStream_t stream) {
    const float* x  = (const float*)d_in[0];
    const int*   ei = (const int*)d_in[1];
    const int*   src = ei;
    const int*   dst = ei + N_EDGES;
    const float* W1 = (const float*)d_in[2];
    const float* b1 = (const float*)d_in[3];
    const float* W2 = (const float*)d_in[4];
    const float* b2 = (const float*)d_in[5];
    const float* W3 = (const float*)d_in[6];
    const float* b3 = (const float*)d_in[7];
    float* out = (float*)d_out;

    const int N = N_NODES, E = N_EDGES;

    char* p = (char*)d_ws;
    int*   cursor   = (int*)p;              p += 256 * 4;
    int*   gbase    = (int*)p;              p += 256 * 4;
    float* dinv     = (float*)p;            p += (size_t)N * 4;
    int*   row_ptr  = (int*)p;              p += (size_t)(N + 4) * 4;
    int*   bucketed = (int*)p;              p += (size_t)NBUCK * BCAP * 4;
    int*   csr_src  = (int*)p;              p += (size_t)E * 4;
    p = (char*)(((size_t)p + 15) & ~(size_t)15);
    _Float16* bufA  = (_Float16*)p;         p += (size_t)N * 64 * 2;  // fp16 tS
    p = (char*)(((size_t)p + 15) & ~(size_t)15);
    _Float16* bufB  = (_Float16*)p;         p += (size_t)N * 64 * 2;  // fp16 h

    // ---- counting-sort CSR build ----
    zero_small<<<1, 256, 0, stream>>>(cursor, NBUCK);
    multisplit<<<NCHUNK, 256, 0, stream>>>(src, dst, cursor, bucketed, E);
    bucket_scan<<<1, 256, 0, stream>>>(cursor, gbase);
    build_csr<<<NBUCK, 512, 0, stream>>>(bucketed, gbase, row_ptr, dinv, csr_src, N);

    const int aggGrid = (N + 3) / 4;
    const int gemmGrid = (N + 63) / 64;

    // layer 1: x fp32 -> tS fp16; aggregate+relu -> h fp16
    gemm_rt<128, 64, float><<<gemmGrid, 256, 0, stream>>>(x, W1, dinv, bufA, N);
    aggregate64b<true><<<aggGrid, 256, 0, stream>>>(bufA, row_ptr, csr_src, dinv, b1, bufB, N);

    // layer 2: h fp16 -> tS fp16; aggregate+relu -> h fp16
    gemm_rt<64, 64, _Float16><<<gemmGrid, 256, 0, stream>>>(bufB, W2, dinv, bufA, N);
    aggregate64b<true><<<aggGrid, 256, 0, stream>>>(bufA, row_ptr, csr_src, dinv, b2, bufB, N);

    // layer 3: h fp16 -> tS40 fp16; aggregate -> out fp32
    gemm_rt<64, 40, _Float16><<<gemmGrid, 256, 0, stream>>>(bufB, W3, dinv, bufA, N);
    aggregate40v<<<aggGrid, 256, 0, stream>>>(bufA, row_ptr, csr_src, dinv, b3, out, N);
}

// Round 12
// 329.119 us; speedup vs baseline: 1.1159x; 1.0526x over previous
//
#include <hip/hip_runtime.h>

#define N_NODES 100000
#define N_EDGES 1600000
#define NBUCK 196          // 512 nodes per bucket (dst >> 9)
#define BCAP 9600          // expected 8192 +- 91; >15 sigma headroom
#define CH 4096            // edges per multisplit chunk
#define NCHUNK ((N_EDGES + CH - 1) / CH)  // 391

typedef __attribute__((ext_vector_type(2))) _Float16 half2v;
typedef __attribute__((ext_vector_type(4))) _Float16 half4v;
typedef __attribute__((ext_vector_type(8))) _Float16 half8v;
typedef __attribute__((ext_vector_type(4))) float f32x4;

__device__ __forceinline__ float4 loadX4(const float* X, size_t idx) {
    return *(const float4*)(X + idx);
}
__device__ __forceinline__ float4 loadX4(const _Float16* X, size_t idx) {
    half4v h = *(const half4v*)(X + idx);
    return make_float4((float)h.x, (float)h.y, (float)h.z, (float)h.w);
}

// ---------------- counting-sort CSR build (R9, unchanged) ----------------

__global__ __launch_bounds__(256) void zero_small(int* p, int n) {
    int i = blockIdx.x * blockDim.x + threadIdx.x;
    if (i < n) p[i] = 0;
}

__global__ __launch_bounds__(256) void multisplit(const int* __restrict__ src,
                                                  const int* __restrict__ dst,
                                                  int* cursor,
                                                  int* __restrict__ bucketed, int e) {
    __shared__ int cnt[NBUCK];
    __shared__ int basel[NBUCK];
    const int t = threadIdx.x;
    const int base_e = blockIdx.x * CH;

    int myS[16], myD[16];
    for (int i = t; i < NBUCK; i += 256) cnt[i] = 0;
    __syncthreads();

#pragma unroll
    for (int k = 0; k < 16; ++k) {
        int i = base_e + k * 256 + t;
        if (i < e) {
            myS[k] = src[i];
            myD[k] = dst[i];
            atomicAdd(&cnt[myD[k] >> 9], 1);
        } else {
            myD[k] = -1;
        }
    }
    __syncthreads();
    for (int i = t; i < NBUCK; i += 256) basel[i] = atomicAdd(&cursor[i], cnt[i]);
    __syncthreads();
    for (int i = t; i < NBUCK; i += 256) cnt[i] = 0;
    __syncthreads();

#pragma unroll
    for (int k = 0; k < 16; ++k) {
        if (myD[k] >= 0) {
            int b = myD[k] >> 9;
            int pos = basel[b] + atomicAdd(&cnt[b], 1);
            if (pos < BCAP)
                bucketed[(size_t)b * BCAP + pos] = ((myD[k] & 511) << 17) | myS[k];
        }
    }
}

__global__ __launch_bounds__(256) void bucket_scan(const int* __restrict__ cursor,
                                                   int* __restrict__ gbase) {
    __shared__ int sm[256];
    const int t = threadIdx.x;
    int v = (t < NBUCK) ? cursor[t] : 0;
    sm[t] = v;
    __syncthreads();
    for (int off = 1; off < 256; off <<= 1) {
        int u = (t >= off) ? sm[t - off] : 0;
        __syncthreads();
        sm[t] += u;
        __syncthreads();
    }
    if (t < NBUCK) gbase[t] = sm[t] - v;
    if (t == NBUCK - 1) gbase[NBUCK] = sm[t];
}

__global__ __launch_bounds__(512) void build_csr(const int* __restrict__ bucketed,
                                                 const int* __restrict__ gbase,
                                                 int* __restrict__ row_ptr,
                                                 float* __restrict__ dinv,
                                                 int* __restrict__ csr_src, int n) {
    __shared__ int vals[BCAP];
    __shared__ int cnt[512];
    __shared__ int lcur[512];
    const int b = blockIdx.x;
    const int t = threadIdx.x;
    const int nb0 = b * 512;
    const int nn = min(512, n - nb0);
    const int gb = gbase[b];
    const int m = gbase[b + 1] - gb;

    cnt[t] = 0;
    __syncthreads();
    for (int i = t; i < m; i += 512) {
        int v = bucketed[(size_t)b * BCAP + i];
        vals[i] = v;
        atomicAdd(&cnt[v >> 17], 1);
    }
    __syncthreads();

    int deg = cnt[t];
    for (int off = 1; off < 512; off <<= 1) {
        int u = (t >= off) ? cnt[t - off] : 0;
        __syncthreads();
        cnt[t] += u;
        __syncthreads();
    }
    int offv = cnt[t] - deg;
    __syncthreads();
    cnt[t] = offv;
    lcur[t] = 0;
    if (t < nn) {
        row_ptr[nb0 + t] = gb + offv;
        dinv[nb0 + t] = rsqrtf((float)(deg + 1));
    }
    if (b == NBUCK - 1 && t == 0) row_ptr[n] = gb + m;
    __syncthreads();

    for (int i = t; i < m; i += 512) {
        int v = vals[i];
        int node = v >> 17;
        int pos = atomicAdd(&lcur[node], 1);
        csr_src[gb + cnt[node] + pos] = v & 0x1FFFF;
    }
}

// ---------------- W pre-transpose: Wt[n][k] = fp16(W[k][n]) ----------------

template <int K>
__global__ __launch_bounds__(256) void transpose_w(const float* __restrict__ W,
                                                   _Float16* __restrict__ Wt) {
    int i = blockIdx.x * 256 + threadIdx.x;
    if (i < K * 64) {
        int k = i >> 6, nn = i & 63;
        Wt[(size_t)nn * K + k] = (_Float16)W[i];
    }
}

// ---------------- MFMA GEMM: Y[N,64] = fp16(dinv * X[N,K] @ W) ----------------
// Block 256 = 4 waves; wave w owns rows w*16..+15 x 64 cols (4 16x16 C tiles).
// A frag: A[m=lane&15][k=quad*8+j] from Xl; B frag: Wt[n=lane&15][k] same shape.
// LDS rows padded +8 halves -> inter-lane bank stride 4 mod 32 = 2-way alias (free).

__device__ __forceinline__ void stageX_rows(const float* X, _Float16* Xl, int t,
                                            int row0, int n, int K, int SP) {
    for (int i = t; i < 64 * K / 4; i += 256) {
        int r = i / (K / 4), c = (i % (K / 4)) * 4;
        int grow = min(row0 + r, n - 1);
        float4 v = *(const float4*)(X + (size_t)grow * K + c);
        half4v h = {(_Float16)v.x, (_Float16)v.y, (_Float16)v.z, (_Float16)v.w};
        *(half4v*)(Xl + r * SP + c) = h;
    }
}
__device__ __forceinline__ void stageX_rows(const _Float16* X, _Float16* Xl, int t,
                                            int row0, int n, int K, int SP) {
    for (int i = t; i < 64 * K / 8; i += 256) {
        int r = i / (K / 8), c = (i % (K / 8)) * 8;
        int grow = min(row0 + r, n - 1);
        *(half8v*)(Xl + r * SP + c) = *(const half8v*)(X + (size_t)grow * K + c);
    }
}

template <int K, typename XT>
__global__ __launch_bounds__(256) void gemm_mfma64(const XT* __restrict__ X,
                                                   const _Float16* __restrict__ Wt,
                                                   const float* __restrict__ dinv,
                                                   _Float16* __restrict__ Y, int n) {
    constexpr int SP = K + 8;
    __shared__ _Float16 Xl[64 * SP];
    __shared__ _Float16 Wl[64 * SP];
    const int t = threadIdx.x;
    const int wave = t >> 6, lane = t & 63;
    const int row0 = blockIdx.x * 64;
    const int m = lane & 15, quad = lane >> 4;

    // stage Wt (straight padded copy) and X rows
    for (int i = t; i < 64 * K / 8; i += 256) {
        int r = i / (K / 8), c = (i % (K / 8)) * 8;
        *(half8v*)(Wl + r * SP + c) = *(const half8v*)(Wt + (size_t)r * K + c);
    }
    stageX_rows(X, Xl, t, row0, n, K, SP);
    __syncthreads();

    f32x4 acc[4] = {{0,0,0,0},{0,0,0,0},{0,0,0,0},{0,0,0,0}};
#pragma unroll
    for (int k0 = 0; k0 < K; k0 += 32) {
        half8v a = *(const half8v*)(Xl + (wave * 16 + m) * SP + k0 + quad * 8);
#pragma unroll
        for (int ct = 0; ct < 4; ++ct) {
            half8v b = *(const half8v*)(Wl + (ct * 16 + m) * SP + k0 + quad * 8);
            acc[ct] = __builtin_amdgcn_mfma_f32_16x16x32_f16(a, b, acc[ct], 0, 0, 0);
        }
    }

    // D: col = lane&15 (=m), row = quad*4 + reg
    float dv[4];
#pragma unroll
    for (int r = 0; r < 4; ++r) {
        int row = row0 + wave * 16 + quad * 4 + r;
        dv[r] = dinv[min(row, n - 1)];
    }
#pragma unroll
    for (int ct = 0; ct < 4; ++ct) {
#pragma unroll
        for (int r = 0; r < 4; ++r) {
            int row = row0 + wave * 16 + quad * 4 + r;
            if (row < n)
                Y[(size_t)row * 64 + ct * 16 + m] = (_Float16)(dv[r] * acc[ct][r]);
        }
    }
}

// ---------------- VALU GEMM (layer 3, COUT=40): Y = fp16(dinv * X @ W) ----------------

template <int K, int COUT, typename XT>
__global__ __launch_bounds__(256) void gemm_rt(const XT* __restrict__ X,
                                               const float* __restrict__ W,
                                               const float* __restrict__ dinv,
                                               _Float16* __restrict__ Y, int n) {
    constexpr int KC = 64;
    constexpr int S = KC + 4;
    constexpr int NCH = K / KC;
    __shared__ float Xl[64 * S];
    __shared__ float Wl[KC * COUT];

    const int t = threadIdx.x;
    const int row0 = blockIdx.x * 64;
    const int cg = (t & 15) * 4;
    const int rg = (t >> 4) * 4;

    float acc[4][4] = {};

#pragma unroll
    for (int ch = 0; ch < NCH; ++ch) {
        const int k0 = ch * KC;
        for (int i = t; i < 64 * KC / 4; i += 256) {
            int r = i >> 4;
            int k = (i & 15) * 4;
            int grow = min(row0 + r, n - 1);
            *(float4*)(Xl + r * S + k) = loadX4(X, (size_t)grow * K + k0 + k);
        }
        for (int i = t; i < KC * COUT / 4; i += 256) {
            *(float4*)(Wl + i * 4) = *(const float4*)(W + (size_t)k0 * COUT + (size_t)i * 4);
        }
        __syncthreads();

        if (cg < COUT) {
#pragma unroll 4
            for (int k = 0; k < KC; ++k) {
                float4 w = *(const float4*)(Wl + k * COUT + cg);
                float x0 = Xl[(rg + 0) * S + k];
                float x1 = Xl[(rg + 1) * S + k];
                float x2 = Xl[(rg + 2) * S + k];
                float x3 = Xl[(rg + 3) * S + k];
                acc[0][0] += x0 * w.x; acc[0][1] += x0 * w.y; acc[0][2] += x0 * w.z; acc[0][3] += x0 * w.w;
                acc[1][0] += x1 * w.x; acc[1][1] += x1 * w.y; acc[1][2] += x1 * w.z; acc[1][3] += x1 * w.w;
                acc[2][0] += x2 * w.x; acc[2][1] += x2 * w.y; acc[2][2] += x2 * w.z; acc[2][3] += x2 * w.w;
                acc[3][0] += x3 * w.x; acc[3][1] += x3 * w.y; acc[3][2] += x3 * w.z; acc[3][3] += x3 * w.w;
            }
        }
        __syncthreads();
    }

    if (cg < COUT) {
#pragma unroll
        for (int r = 0; r < 4; ++r) {
            int row = row0 + rg + r;
            if (row < n) {
                float d = dinv[row];
                half4v o = { (_Float16)(d * acc[r][0]), (_Float16)(d * acc[r][1]),
                             (_Float16)(d * acc[r][2]), (_Float16)(d * acc[r][3]) };
                *(half4v*)(Y + (size_t)row * COUT + cg) = o;
            }
        }
    }
}

// ---------------- aggregation, COUT=64, fp16 gather, pk_f16 loop accumulate ----------------
// 8 groups of 8 lanes; group g reads edge (j+g)'s 16B row-part (half8).
// Loop accumulates in packed fp16 (short small-magnitude chains), converts to
// fp32 before the cross-lane butterfly.

template <bool RELU>
__global__ __launch_bounds__(256) void aggregate64b(const _Float16* __restrict__ tS,
                                                    const int* __restrict__ row_ptr,
                                                    const int* __restrict__ csr_src,
                                                    const float* __restrict__ dinv,
                                                    const float* __restrict__ bias,
                                                    _Float16* __restrict__ out, int n) {
    const int lane = threadIdx.x & 63;
    const int node = blockIdx.x * 4 + (threadIdx.x >> 6);
    if (node >= n) return;
    const int g = lane >> 3;
    const int c8 = lane & 7;
    const half8v* tS8 = (const half8v*)tS;

    const int beg = row_ptr[node];
    const int cnt = row_ptr[node + 1] - beg;

    half8v accA, accB;
#pragma unroll
    for (int i = 0; i < 8; ++i) { accA[i] = (_Float16)0; accB[i] = (_Float16)0; }

    for (int j0 = 0; j0 < cnt; j0 += 64) {
        const int m = min(64, cnt - j0);
        int sj = csr_src[beg + j0 + min(lane, m - 1)];

        int j = 0;
        for (; j + 16 <= m; j += 16) {
            int e0 = __shfl(sj, j + g);
            int e1 = __shfl(sj, j + 8 + g);
            half8v v0 = tS8[(size_t)e0 * 8 + c8];
            half8v v1 = tS8[(size_t)e1 * 8 + c8];
            accA += v0;          // 4x v_pk_add_f16
            accB += v1;
        }
        for (; j + 8 <= m; j += 8) {
            int e0 = __shfl(sj, j + g);
            accA += tS8[(size_t)e0 * 8 + c8];
        }
        if (j < m) {
            int idx = j + g;
            int e0 = __shfl(sj, min(idx, m - 1));
            half8v v = tS8[(size_t)e0 * 8 + c8];
            if (idx < m) accB += v;
        }
    }

    // promote to fp32, then butterfly across the 8 edge-groups
    float acc[8];
#pragma unroll
    for (int i = 0; i < 8; ++i) acc[i] = (float)accA[i] + (float)accB[i];
#pragma unroll
    for (int off = 8; off < 64; off <<= 1) {
#pragma unroll
        for (int i = 0; i < 8; ++i) acc[i] += __shfl_xor(acc[i], off);
    }

    if (lane < 8) {
        half8v selfh = tS8[(size_t)node * 8 + c8];
        float4 b0 = *(const float4*)(bias + c8 * 8);
        float4 b1 = *(const float4*)(bias + c8 * 8 + 4);
        const float bb[8] = {b0.x, b0.y, b0.z, b0.w, b1.x, b1.y, b1.z, b1.w};
        float d = dinv[node];
        half8v o;
#pragma unroll
        for (int i = 0; i < 8; ++i) {
            float v = bb[i] + d * (acc[i] + (float)selfh[i]);
            if (RELU) v = fmaxf(v, 0.0f);
            o[i] = (_Float16)v;
        }
        ((half8v*)out)[(size_t)node * 8 + c8] = o;
    }
}

// ---------------- aggregation, COUT=40, fp16 gather, pk_f16 loop accumulate ----------------

__global__ __launch_bounds__(256) void aggregate40v(const _Float16* __restrict__ tS,
                                                    const int* __restrict__ row_ptr,
                                                    const int* __restrict__ csr_src,
                                                    const float* __restrict__ dinv,
                                                    const float* __restrict__ bias,
                                                    float* __restrict__ out, int n) {
    const int lane = threadIdx.x & 63;
    const int node = blockIdx.x * 4 + (threadIdx.x >> 6);
    if (node >= n) return;
    const int g = lane / 20;
    const int c2 = lane - 20 * g;
    const bool act = (g < 3);
    const half2v* tS2 = (const half2v*)tS;

    const int beg = row_ptr[node];
    const int cnt = row_ptr[node + 1] - beg;

    half2v a0 = {(_Float16)0, (_Float16)0}, a1 = a0, a2 = a0, a3 = a0;

    for (int j0 = 0; j0 < cnt; j0 += 64) {
        const int m = min(64, cnt - j0);
        int sj = (lane < m) ? csr_src[beg + j0 + lane] : 0;

        int j = 0;
        for (; j + 12 <= m; j += 12) {
            int i0 = j + g, i1 = j + 3 + g, i2 = j + 6 + g, i3 = j + 9 + g;
            int e0 = __shfl(sj, i0 < m ? i0 : 0);
            int e1 = __shfl(sj, i1 < m ? i1 : 0);
            int e2 = __shfl(sj, i2 < m ? i2 : 0);
            int e3 = __shfl(sj, i3 < m ? i3 : 0);
            half2v v0 = tS2[(size_t)e0 * 20 + c2];
            half2v v1 = tS2[(size_t)e1 * 20 + c2];
            half2v v2 = tS2[(size_t)e2 * 20 + c2];
            half2v v3 = tS2[(size_t)e3 * 20 + c2];
            if (act) { a0 += v0; a1 += v1; a2 += v2; a3 += v3; }
        }
        for (; j + 3 <= m; j += 3) {
            int i0 = j + g;
            int e0 = __shfl(sj, i0 < m ? i0 : 0);
            half2v v0 = tS2[(size_t)e0 * 20 + c2];
            if (act) a0 += v0;
        }
        if (j < m) {
            int idx = j + g;
            int e0 = __shfl(sj, idx < m ? idx : m - 1);
            half2v v = tS2[(size_t)e0 * 20 + c2];
            if (act && idx < m) a1 += v;
        }
    }

    float2 s;
    s.x = ((float)a0.x + (float)a1.x) + ((float)a2.x + (float)a3.x);
    s.y = ((float)a0.y + (float)a1.y) + ((float)a2.y + (float)a3.y);
    float sx1 = __shfl(s.x, lane + 20), sy1 = __shfl(s.y, lane + 20);
    float sx2 = __shfl(s.x, lane + 40), sy2 = __shfl(s.y, lane + 40);
    if (lane < 20) {
        s.x += sx1 + sx2;
        s.y += sy1 + sy2;
        half2v selfh = tS2[(size_t)node * 20 + c2];
        float2 b = ((const float2*)bias)[c2];
        float d = dinv[node];
        float2 o;
        o.x = b.x + d * (s.x + (float)selfh.x);
        o.y = b.y + d * (s.y + (float)selfh.y);
        ((float2*)out)[(size_t)node * 20 + c2] = o;
    }
}

// ---------------- launch ----------------

extern "C" void kernel_launch(void* const* d_in, const int* in_sizes, int n_in,
                              void* d_out, int out_size, void* d_ws, size_t ws_size,
                              hipStream_t stream) {
    const float* x  = (const float*)d_in[0];
    const int*   ei = (const int*)d_in[1];
    const int*   src = ei;
    const int*   dst = ei + N_EDGES;
    const float* W1 = (const float*)d_in[2];
    const float* b1 = (const float*)d_in[3];
    const float* W2 = (const float*)d_in[4];
    const float* b2 = (const float*)d_in[5];
    const float* W3 = (const float*)d_in[6];
    const float* b3 = (const float*)d_in[7];
    float* out = (float*)d_out;

    const int N = N_NODES, E = N_EDGES;

    char* p = (char*)d_ws;
    int*   cursor   = (int*)p;              p += 256 * 4;
    int*   gbase    = (int*)p;              p += 256 * 4;
    float* dinv     = (float*)p;            p += (size_t)N * 4;
    int*   row_ptr  = (int*)p;              p += (size_t)(N + 4) * 4;
    int*   bucketed = (int*)p;              p += (size_t)NBUCK * BCAP * 4;
    int*   csr_src  = (int*)p;              p += (size_t)E * 4;
    p = (char*)(((size_t)p + 15) & ~(size_t)15);
    _Float16* Wt1   = (_Float16*)p;         p += (size_t)64 * 128 * 2;
    _Float16* Wt2   = (_Float16*)p;         p += (size_t)64 * 64 * 2;
    _Float16* bufA  = (_Float16*)p;         p += (size_t)N * 64 * 2;  // fp16 tS
    p = (char*)(((size_t)p + 15) & ~(size_t)15);
    _Float16* bufB  = (_Float16*)p;         p += (size_t)N * 64 * 2;  // fp16 h

    // ---- counting-sort CSR build + W pre-transpose ----
    zero_small<<<1, 256, 0, stream>>>(cursor, NBUCK);
    transpose_w<128><<<32, 256, 0, stream>>>(W1, Wt1);
    transpose_w<64><<<16, 256, 0, stream>>>(W2, Wt2);
    multisplit<<<NCHUNK, 256, 0, stream>>>(src, dst, cursor, bucketed, E);
    bucket_scan<<<1, 256, 0, stream>>>(cursor, gbase);
    build_csr<<<NBUCK, 512, 0, stream>>>(bucketed, gbase, row_ptr, dinv, csr_src, N);

    const int aggGrid = (N + 3) / 4;
    const int gemmGrid = (N + 63) / 64;

    // layer 1: x fp32 -> tS fp16 (MFMA); aggregate+relu -> h fp16
    gemm_mfma64<128, float><<<gemmGrid, 256, 0, stream>>>(x, Wt1, dinv, bufA, N);
    aggregate64b<true><<<aggGrid, 256, 0, stream>>>(bufA, row_ptr, csr_src, dinv, b1, bufB, N);

    // layer 2: h fp16 -> tS fp16 (MFMA); aggregate+relu -> h fp16
    gemm_mfma64<64, _Float16><<<gemmGrid, 256, 0, stream>>>(bufB, Wt2, dinv, bufA, N);
    aggregate64b<true><<<aggGrid, 256, 0, stream>>>(bufA, row_ptr, csr_src, dinv, b2, bufB, N);

    // layer 3: h fp16 -> tS40 fp16 (VALU); aggregate -> out fp32
    gemm_rt<64, 40, _Float16><<<gemmGrid, 256, 0, stream>>>(bufB, W3, dinv, bufA, N);
    aggregate40v<<<aggGrid, 256, 0, stream>>>(bufA, row_ptr, csr_src, dinv, b3, out, N);
}